// Round 7
// baseline (1240.049 us; speedup 1.0000x reference)
//
#include <hip/hip_runtime.h>

#define V 16000
#define E 256
#define H 512
#define HP 516     // padded LDS h row stride (4-float pad: bank groups 4r)
#define BB 8       // batch rows
#define T 12       // lenseq
#define NB 250     // persistent blocks: 250*64 == 16000 exactly (1 block/CU)
#define NBS 256    // psum/pval/pidx stride (padded)
#define TPB 1024   // 16 waves/block
#define CPB 64     // vocab cols per block: 64*4B = 256B row slice, LINE-ALIGNED
#define AGENT __HIP_MEMORY_SCOPE_AGENT

typedef float vfloat4 __attribute__((ext_vector_type(4)));

// Greedy degeneracy verified (R3). Persistent kernel since R4. w_out in LDS
// since R9. Writer saga R10-R15: WRITE_SIZE amplification (32-103MB) is
// invariant to store pattern AND the NT flag, and never correlated with dur
// -> red herring, writer frozen as R14's NT full-line stores. R15's flat
// barrier regressed 65us: 2000 pollers on 8 write-hot lines >> tree with 1
// read-only epoch word. R16 (this round): tree barriers kept; phase-C's
// global reduce FUSED into bar2 -- block0 (already the detect block) reduces
// psum/pval/pidx for all 8 rows, computes next tokens, publishes {S[8],
// newx[8]} in ONE 64B payload line, then releases epoch2. 249 blocks read 1
// line instead of 24KB scattered agent loads + butterfly each. bar1 counts
// only the 64 GRU-producer arrivals (full bar2 separates parity hazards:
// A(t+1) vs B(t-1) readers are fenced by everyone's bar2(t) arrival).
// Payload overwrite at t+1 is gated behind every block's bar2(t+1) arrival,
// which follows its payload(t) read in program order -> no race.

// LDS layout (floats)
constexpr int W_FL   = CPB * 512;            // 32768  swizzled w slice (128KB)
constexpr int SH_OFF = W_FL;                 // s_h   [8][516]
constexpr int SP_OFF = SH_OFF + BB * HP;     // s_part 64*48 (A) / s_e [8][65] (B/C)
constexpr int RS_OFF = SP_OFF + 64 * 48;     // s_rsum [16][8]
constexpr int RV_OFF = RS_OFF + 128;         // s_rval
constexpr int RI_OFF = RV_OFF + 128;         // s_ridx (int)
constexpr int SS_OFF = RI_OFF + 128;         // s_S   [8]
constexpr int XN_OFF = SS_OFF + 8;           // s_Xn  [8] (int)
constexpr int X_OFF  = XN_OFF + 8;           // s_X   [8] (int)
constexpr int SMEM_FL = X_OFF + 8;
constexpr size_t SMEM_BYTES = (size_t)SMEM_FL * 4;   // 161,504 B < 160 KiB

// cnt line map (16 ints per line):
//   lines 0..62 : bar2 leaf counters (62x4 + 2 = 250 arrivals)
//   line  63    : epochA word (h-ready publish)
//   lines 64,65 : barA arrival counters (32 each from blocks 0..63)
//   line  66    : epoch2 word (reduce-done publish)
//   line  67    : payload: [0..7]=S bits, [8..15]=next tokens
constexpr int CNT_LINES = 80;

__device__ __forceinline__ float dot4(float4 a, float4 b) {
    return a.x * b.x + a.y * b.y + a.z * b.z + a.w * b.w;
}

__global__ __launch_bounds__(256) void kinit(const float* __restrict__ hidden,
                                             float* __restrict__ hA,
                                             int* __restrict__ cnt,
                                             int* __restrict__ epoch) {
    int idx = blockIdx.x * 256 + threadIdx.x;
    if (idx < BB * H) hA[idx] = hidden[idx];
    if (idx < CNT_LINES * 16) cnt[idx] = 0;
    if (idx == 0) epoch[0] = 0;
}

// bar1 (h-ready): arrivals from the 64 GRU blocks on 2 lines; block0 detects
// and publishes epochA; everyone else polls the single read-only epochA word.
__device__ __forceinline__ void barA(int* __restrict__ cnt, int ep) {
    __syncthreads();
    if (blockIdx.x < 64 && threadIdx.x == 0)
        __hip_atomic_fetch_add(&cnt[(64 + (blockIdx.x & 1)) * 16], 1,
                               __ATOMIC_RELEASE, AGENT);
    if (blockIdx.x == 0) {
        if (threadIdx.x < 2) {
            while (__hip_atomic_load(&cnt[(64 + threadIdx.x) * 16],
                                     __ATOMIC_RELAXED, AGENT) < 32 * ep)
                __builtin_amdgcn_s_sleep(1);
        }
        __syncthreads();
        if (threadIdx.x == 0)
            __hip_atomic_store(&cnt[63 * 16], ep, __ATOMIC_RELEASE, AGENT);
    } else {
        if (threadIdx.x == 0) {
            while (__hip_atomic_load(&cnt[63 * 16], __ATOMIC_ACQUIRE, AGENT) < ep)
                __builtin_amdgcn_s_sleep(1);
        }
    }
    __builtin_amdgcn_fence(__ATOMIC_ACQUIRE, "workgroup");
    __syncthreads();
}

__global__ __launch_bounds__(TPB, 4) void kmain(
    const float* __restrict__ emb_tab,
    const float* __restrict__ w_ih,
    const float* __restrict__ w_hh,
    const float* __restrict__ b_ih,
    const float* __restrict__ b_hh,
    const float* __restrict__ w_out,
    const float* __restrict__ b_out,
    float* __restrict__ hA,
    float* __restrict__ hB,
    float* __restrict__ psum,   // [2][8][NBS]
    float* __restrict__ pval,
    int* __restrict__ pidx,
    int* __restrict__ cnt,
    int* __restrict__ epoch,
    float* __restrict__ out)
{
    extern __shared__ float smem[];
    float* w_lds  = smem;
    float* s_h    = smem + SH_OFF;
    float* s_part = smem + SP_OFF;
    float* s_e    = smem + SP_OFF;          // alias: phase-B/C e buffer [8][65]
    float* s_rsum = smem + RS_OFF;
    float* s_rval = smem + RV_OFF;
    int*   s_ridx = (int*)(smem + RI_OFF);
    float* s_S    = smem + SS_OFF;
    int*   s_Xn   = (int*)(smem + XN_OFF);
    int*   s_X    = (int*)(smem + X_OFF);

    const int blk = blockIdx.x, tid = threadIdx.x;
    int* pay = &cnt[67 * 16];
    (void)epoch;

    // ---- stage this block's w_out slice into LDS, swizzled, ONCE ----------
    // layout: w_lds[col*512 + (k ^ ((col&7)<<2) ^ (((k>>5)&7)<<2))]
    for (int i = tid; i < CPB * 128; i += TPB) {
        int col = i >> 7;
        int q4  = (i & 127) << 2;
        int vv  = blk * CPB + col;          // always < V (250*64 == 16000)
        float4 w4 = *(const float4*)(w_out + (size_t)vv * H + q4);
        int sw = q4 ^ ((col & 7) << 2) ^ (((q4 >> 5) & 7) << 2);
        *(float4*)(w_lds + col * 512 + sw) = w4;
    }
    if (tid < BB) s_X[tid] = 1;             // SOS
    __syncthreads();

    // ---- phase-B lane mapping: rh=bits0-1, kq=bits2-5 (16 K-chunks of 32)
    // wave: rowhalf=bit0, col-slot cs=bits1-4; per pass p: col = p*8 + cs
    const int lane = tid & 63;
    const int wv   = tid >> 6;              // 0..15
    const int rh   = lane & 3;
    const int kq   = (lane >> 2) & 15;      // K chunk (32 floats)
    const int rowhalf = wv & 1;
    const int cs   = wv >> 1;               // 0..7
    const int r    = rowhalf * 4 + rh;      // 0..7
    const int xw   = (cs ^ (kq & 7)) << 2;  // w swizzle for this (col-slot,kq)
    const int hswz = (kq & 7) << 2;         // h swizzle for this kq

    // b_out is step-invariant: hoist the 8 per-pass values into VGPRs once
    float bo[8];
#pragma unroll
    for (int p = 0; p < 8; p++) bo[p] = b_out[blk * CPB + p * 8 + cs];

    for (int t = 0; t < T; t++) {
        const float* h_cur = (t & 1) ? hB : hA;
        float*       h_nxt = (t & 1) ? hA : hB;
        const int par = t & 1;

        // ---------------- phase A: GRU cell (blocks 0..63) ----------------
        if (blk < 64) {                     // stage h_cur into s_h (linear)
            int hr = tid >> 7, k4 = (tid & 127) << 2;
            const unsigned long long* p =
                (const unsigned long long*)(h_cur + hr * H + k4);
            union { unsigned long long u; float f[2]; } c0, c1;
            c0.u = __hip_atomic_load(p,     __ATOMIC_RELAXED, AGENT);
            c1.u = __hip_atomic_load(p + 1, __ATOMIC_RELAXED, AGENT);
            *(float4*)(s_h + hr * HP + k4) =
                make_float4(c0.f[0], c0.f[1], c1.f[0], c1.f[1]);
        }
        __syncthreads();
        if (blk < 64 && tid < 512) {
            const int jl = tid >> 6;        // 0..7
            const int ar = (tid >> 3) & 7;  // row
            const int kq8 = tid & 7;        // K split 8
            const int j  = blk * 8 + jl;
            const int pair = jl * 8 + ar;
            float gir = 0.f, giz = 0.f, gin = 0.f, ghr = 0.f, ghz = 0.f, ghn = 0.f;
            {
                const float* erow = emb_tab + (size_t)s_X[ar] * E;
                const float* w0 = w_ih + (size_t)j * E;
                const float* w1 = w0 + (size_t)H * E;
                const float* w2 = w1 + (size_t)H * E;
                const int k0 = kq8 * (E / 8);
                for (int k = 0; k < E / 8; k += 4) {
                    float4 ev = *(const float4*)(erow + k0 + k);
                    gir += dot4(*(const float4*)(w0 + k0 + k), ev);
                    giz += dot4(*(const float4*)(w1 + k0 + k), ev);
                    gin += dot4(*(const float4*)(w2 + k0 + k), ev);
                }
            }
            {
                const float* hrow = s_h + ar * HP;
                const float* w0 = w_hh + (size_t)j * H;
                const float* w1 = w0 + (size_t)H * H;
                const float* w2 = w1 + (size_t)H * H;
                const int k0 = kq8 * (H / 8);
                for (int k = 0; k < H / 8; k += 4) {
                    float4 hv = *(const float4*)(hrow + k0 + k);
                    ghr += dot4(*(const float4*)(w0 + k0 + k), hv);
                    ghz += dot4(*(const float4*)(w1 + k0 + k), hv);
                    ghn += dot4(*(const float4*)(w2 + k0 + k), hv);
                }
            }
            float* sp = s_part + pair * 48;
            sp[0 * 8 + kq8] = gir; sp[1 * 8 + kq8] = giz; sp[2 * 8 + kq8] = gin;
            sp[3 * 8 + kq8] = ghr; sp[4 * 8 + kq8] = ghz; sp[5 * 8 + kq8] = ghn;
        }
        __syncthreads();
        if (blk < 64 && tid < 512 && (tid & 7) == 0) {
            const int pair = (tid >> 6) * 8 + ((tid >> 3) & 7);
            const int jl = pair >> 3, ar = pair & 7;
            const int j  = blk * 8 + jl;
            const float* sp2 = s_part + pair * 48;
            float G[6];
#pragma unroll
            for (int gg = 0; gg < 6; gg++) {
                float s = 0.f;
#pragma unroll
                for (int q = 0; q < 8; q++) s += sp2[gg * 8 + q];
                G[gg] = s;
            }
            float ir  = G[0] + b_ih[j],         hr_ = G[3] + b_hh[j];
            float iz  = G[1] + b_ih[H + j],     hz  = G[4] + b_hh[H + j];
            float inn = G[2] + b_ih[2 * H + j], hn  = G[5] + b_hh[2 * H + j];
            float rg = 1.f / (1.f + __expf(-(ir + hr_)));
            float zg = 1.f / (1.f + __expf(-(iz + hz)));
            float ng = tanhf(inn + rg * hn);
            float ho = s_h[ar * HP + j];
            int xr = s_X[ar];
            bool dn = (xr == 0) || (xr == 2);
            float hv = dn ? ho : ((1.f - zg) * ng + zg * ho);
            __hip_atomic_store(&h_nxt[ar * H + j], hv, __ATOMIC_RELAXED, AGENT);
        }
        barA(cnt, t + 1);

        // -------- phase B: logits from LDS-resident w ----------------------
        {   // stage h_nxt, kq-swizzled (layout: s_h[hr*HP + (k ^ ((k>>5&7)<<2))])
            int hr = tid >> 7, k4 = (tid & 127) << 2;
            const unsigned long long* p =
                (const unsigned long long*)(h_nxt + hr * H + k4);
            union { unsigned long long u; float f[2]; } c0, c1;
            c0.u = __hip_atomic_load(p,     __ATOMIC_RELAXED, AGENT);
            c1.u = __hip_atomic_load(p + 1, __ATOMIC_RELAXED, AGENT);
            int sw = k4 ^ (((k4 >> 5) & 7) << 2);
            *(float4*)(s_h + hr * HP + sw) =
                make_float4(c0.f[0], c0.f[1], c1.f[0], c1.f[1]);
        }
        __syncthreads();
        {
            // h chunk -> 32 VGPRs, read ONCE per step
            float4 hreg[8];
            const float* hb = s_h + r * HP + kq * 32;
#pragma unroll
            for (int i = 0; i < 8; i++)
                hreg[i] = *(const float4*)(hb + ((4 * i) ^ hswz));

            float s_acc = 0.f, bv = -1.f; int bi = 0x7fffffff;
#pragma unroll
            for (int p = 0; p < 8; p++) {
                const int col = p * 8 + cs;
                const int vv  = blk * CPB + col;
                const float* wb = w_lds + col * 512 + kq * 32;
                float acc = 0.f;
#pragma unroll
                for (int i = 0; i < 8; i++) {
                    float4 w4 = *(const float4*)(wb + ((4 * i) ^ xw));
                    acc += dot4(w4, hreg[i]);
                }
                // full-K sum across the 16 kq lanes (bits 2-5); butterfly is
                // commutative-add -> bitwise identical on every lane
                acc += __shfl_xor(acc, 4, 64);
                acc += __shfl_xor(acc, 8, 64);
                acc += __shfl_xor(acc, 16, 64);
                acc += __shfl_xor(acc, 32, 64);
                float ee = __expf(acc + bo[p]);
                if (kq == 0) s_e[r * 65 + col] = ee;  // stash for phase-C write
                s_acc += ee;
                if (ee > bv) { bv = ee; bi = vv; }  // earlier pass = smaller v
            }
            if (kq == 0) {                  // designated: real per-r results
                s_rsum[wv * 8 + r] = s_acc;
                s_rval[wv * 8 + r] = bv;
                s_ridx[wv * 8 + r] = bi;
            } else if (kq == 1) {           // neutral fill for other row-half
                int ro = (1 - rowhalf) * 4 + rh;
                s_rsum[wv * 8 + ro] = 0.f;
                s_rval[wv * 8 + ro] = -1.f;
                s_ridx[wv * 8 + ro] = 0x7fffffff;
            }
        }
        __syncthreads();
        if (tid < 64) {                     // reduce 16 waves -> per-row, store
            float s  = s_rsum[tid] + s_rsum[tid + 64];
            float av = s_rval[tid], bv2 = s_rval[tid + 64];
            int   ai = s_ridx[tid], bi2 = s_ridx[tid + 64];
            float bv = av; int bi = ai;
            if (bv2 > bv || (bv2 == bv && bi2 < bi)) { bv = bv2; bi = bi2; }
#pragma unroll
            for (int m = 8; m <= 32; m <<= 1) {
                s += __shfl_xor(s, m, 64);
                float ov = __shfl_xor(bv, m, 64);
                int   oi = __shfl_xor(bi, m, 64);
                if (ov > bv || (ov == bv && oi < bi)) { bv = ov; bi = oi; }
            }
            if (tid < 8) {
                int o = (par * 8 + tid) * NBS + blk;
                __hip_atomic_store(&psum[o], s,  __ATOMIC_RELAXED, AGENT);
                __hip_atomic_store(&pval[o], bv, __ATOMIC_RELAXED, AGENT);
                __hip_atomic_store(&pidx[o], bi, __ATOMIC_RELAXED, AGENT);
            }
        }

        // ---- bar2 fused with the global reduce: block0 detects arrivals,
        // reduces all 8 rows, publishes {S, newx} payload, releases epoch2.
        __syncthreads();
        if (tid == 0) {
            int g = blk >> 2;
            __hip_atomic_fetch_add(&cnt[g * 16], 1, __ATOMIC_RELEASE, AGENT);
        }
        if (blk == 0) {
            if (tid < 63) {
                int expct = (tid == 62) ? 2 : 4;   // 62*4 + 2 = 250
                while (__hip_atomic_load(&cnt[tid * 16],
                                         __ATOMIC_RELAXED, AGENT) < expct * (t + 1))
                    __builtin_amdgcn_s_sleep(1);
            }
            __syncthreads();                // gate all 16 waves on detection
            if (wv < 8) {                   // wave w reduces row w
                const int base = (par * 8 + wv) * NBS;
                float s = 0.f, bv = -1.f; int bi = 0x7fffffff;
#pragma unroll
                for (int c = 0; c < 4; c++) {
                    int idx = lane + 64 * c;
                    if (idx < NB) {
                        int o = base + idx;
                        s += __hip_atomic_load(&psum[o], __ATOMIC_RELAXED, AGENT);
                        float ov = __hip_atomic_load(&pval[o], __ATOMIC_RELAXED, AGENT);
                        int   oi = __hip_atomic_load(&pidx[o], __ATOMIC_RELAXED, AGENT);
                        if (ov > bv || (ov == bv && oi < bi)) { bv = ov; bi = oi; }
                    }
                }
                for (int m = 1; m < 64; m <<= 1) {
                    s += __shfl_xor(s, m, 64);
                    float ov = __shfl_xor(bv, m, 64);
                    int   oi = __shfl_xor(bi, m, 64);
                    if (ov > bv || (ov == bv && oi < bi)) { bv = ov; bi = oi; }
                }
                if (lane == 0) {
                    int xo = s_X[wv];
                    int nx = ((xo == 0) || (xo == 2)) ? 0 : bi;
                    s_S[wv]  = s;
                    s_Xn[wv] = nx;
                    __hip_atomic_store(&pay[wv], __float_as_int(s),
                                       __ATOMIC_RELAXED, AGENT);
                    __hip_atomic_store(&pay[8 + wv], nx,
                                       __ATOMIC_RELAXED, AGENT);
                }
            }
            __syncthreads();
            if (tid == 0)
                __hip_atomic_store(&cnt[66 * 16], t + 1, __ATOMIC_RELEASE, AGENT);
        } else {
            if (tid == 0) {
                while (__hip_atomic_load(&cnt[66 * 16],
                                         __ATOMIC_ACQUIRE, AGENT) < t + 1)
                    __builtin_amdgcn_s_sleep(1);
            }
            __syncthreads();                // all threads gated on epoch2
            if (tid < 8)
                s_S[tid] = __int_as_float(
                    __hip_atomic_load(&pay[tid], __ATOMIC_RELAXED, AGENT));
            else if (tid < 16)
                s_Xn[tid - 8] =
                    __hip_atomic_load(&pay[tid], __ATOMIC_RELAXED, AGENT);
        }
        __builtin_amdgcn_fence(__ATOMIC_ACQUIRE, "workgroup");
        __syncthreads();

        // ------- phase C: out write (old s_X mask) + x update from payload -
        {   // out write: FULL-LINE NT vfloat4 stores. Row slice = 256B aligned.
            float* out_t = out + (size_t)t * BB * V;
            if (tid < 128) {
                int row = tid >> 4;         // 0..7
                int c4  = (tid & 15) << 2;  // 0,4,...,60
                int xr = s_X[row];
                bool dn = (xr == 0) || (xr == 2);
                float inv = 1.f / s_S[row];
                int vbase = blk * CPB + c4;
                vfloat4 o4;
                o4.x = dn ? ((vbase + 0 == 0) ? 1.f : 0.f) : s_e[row * 65 + c4 + 0] * inv;
                o4.y = dn ? ((vbase + 1 == 0) ? 1.f : 0.f) : s_e[row * 65 + c4 + 1] * inv;
                o4.z = dn ? ((vbase + 2 == 0) ? 1.f : 0.f) : s_e[row * 65 + c4 + 2] * inv;
                o4.w = dn ? ((vbase + 3 == 0) ? 1.f : 0.f) : s_e[row * 65 + c4 + 3] * inv;
                __builtin_nontemporal_store(o4,
                    (vfloat4*)(out_t + (size_t)row * V + vbase));
            }
        }
        __syncthreads();
        if (tid < 8) s_X[tid] = s_Xn[tid];  // newx already done-masked
        __syncthreads();
    }
}

extern "C" void kernel_launch(void* const* d_in, const int* in_sizes, int n_in,
                              void* d_out, int out_size, void* d_ws, size_t ws_size,
                              hipStream_t stream) {
    (void)in_sizes; (void)n_in; (void)out_size; (void)ws_size;
    const float* hidden    = (const float*)d_in[0];
    const float* embedding = (const float*)d_in[1];
    const float* w_ih      = (const float*)d_in[2];
    const float* w_hh      = (const float*)d_in[3];
    const float* b_ih      = (const float*)d_in[4];
    const float* b_hh      = (const float*)d_in[5];
    const float* w_out     = (const float*)d_in[6];
    const float* b_out     = (const float*)d_in[7];
    float* out = (float*)d_out;

    float* ws    = (float*)d_ws;
    float* hA    = ws;                        // 4096
    float* hB    = hA + BB * H;               // 4096
    float* psum  = hB + BB * H;               // 2*8*NBS
    float* pval  = psum + 2 * 8 * NBS;        // 2*8*NBS
    int*   pidx  = (int*)(pval + 2 * 8 * NBS);// 2*8*NBS
    int*   cnt   = pidx + 2 * 8 * NBS;        // CNT_LINES*16 padded counters
    int*   epoch = cnt + CNT_LINES * 16;      // 1 (unused, kept for layout)

    hipFuncSetAttribute((const void*)kmain,
        hipFuncAttributeMaxDynamicSharedMemorySize,
        (int)SMEM_BYTES);

    kinit<<<16, 256, 0, stream>>>(hidden, hA, cnt, epoch);
    kmain<<<NB, TPB, SMEM_BYTES, stream>>>(embedding, w_ih, w_hh, b_ih, b_hh,
                                           w_out, b_out, hA, hB, psum, pval,
                                           pidx, cnt, epoch, out);
}

// Round 8
// 612.152 us; speedup vs baseline: 2.0257x; 2.0257x over previous
//
#include <hip/hip_runtime.h>

#define V 16000
#define E 256
#define H 512
#define HP 516     // padded LDS h row stride (4-float pad: bank groups 4r)
#define BB 8       // batch rows
#define T 12       // lenseq
#define NB 250     // persistent blocks: 250*64 == 16000 exactly (1 block/CU)
#define NBS 256    // pq stride (padded)
#define TPB 1024   // 16 waves/block
#define CPB 64     // vocab cols per block: 64*4B = 256B row slice, LINE-ALIGNED
#define BBH (BB * H)
#define AGENT __HIP_MEMORY_SCOPE_AGENT

typedef float vfloat4 __attribute__((ext_vector_type(4)));

// Greedy degeneracy verified (R3). Persistent kernel since R4. w_out in LDS
// since R9. Writer saga R10-R15: WRITE_SIZE amplification is invariant to
// store pattern/NT flag and uncorrelated with dur -> red herring; writer
// frozen (NT full-line). Barrier saga R15/R16: flat barrier -65us (2000
// pollers on write-hot lines), fused serial reduce + ACQUIRE-spin -690us
// (invalidate storm + serialized cross-XCD reduce). R14 tree barrier is the
// proven structure -- restored VERBATIM. R17 (this round): kill agent-scope
// atomic data ops instead. All inter-block data buffers ROTATE per step
// (hbuf[13], pq[12]) so every line is write-once/read-first-touch ->
// plain coalesced float4 loads/stores are coherence-safe (release-add at
// barrier arrival flushes prior plain stores; readers never hold stale
// lines). Phase C: 12 scalar ~800cy agent loads/lane -> 4 coalesced float4
// loads of packed {sum,max,idx} triplets.

// LDS layout (floats)
constexpr int W_FL   = CPB * 512;            // 32768  swizzled w slice (128KB)
constexpr int SH_OFF = W_FL;                 // s_h   [8][516]
constexpr int SP_OFF = SH_OFF + BB * HP;     // s_part 64*48 (A) / s_e [8][65] (B/C)
constexpr int RS_OFF = SP_OFF + 64 * 48;     // s_rsum [16][8]
constexpr int RV_OFF = RS_OFF + 128;         // s_rval
constexpr int RI_OFF = RV_OFF + 128;         // s_ridx (int)
constexpr int SS_OFF = RI_OFF + 128;         // s_S   [8]
constexpr int XN_OFF = SS_OFF + 8;           // s_Xn  [8] (int)
constexpr int X_OFF  = XN_OFF + 8;           // s_X   [8] (int)
constexpr int SMEM_FL = X_OFF + 8;
constexpr size_t SMEM_BYTES = (size_t)SMEM_FL * 4;   // 161,504 B < 160 KiB

__device__ __forceinline__ float dot4(float4 a, float4 b) {
    return a.x * b.x + a.y * b.y + a.z * b.z + a.w * b.w;
}

__global__ __launch_bounds__(256) void kinit(const float* __restrict__ hidden,
                                             float* __restrict__ hbuf,
                                             int* __restrict__ leaf,
                                             int* __restrict__ epoch) {
    int idx = blockIdx.x * 256 + threadIdx.x;
    if (idx < BBH) hbuf[idx] = hidden[idx];
    if (idx < 64 * 16) leaf[idx] = 0;
    if (idx == 0) epoch[0] = 0;
}

// R14 tree barrier VERBATIM: leaf arrival (63 leaves: blk>>2; leaf 62 has 2)
// -> block0 watches leaves -> publishes epoch -> others poll ONE word RELAXED.
__device__ __forceinline__ void gridbar(int* __restrict__ leaf,
                                        int* __restrict__ epoch, int ep) {
    __syncthreads();
    if (threadIdx.x == 0) {
        int g = blockIdx.x >> 2;
        __hip_atomic_fetch_add(&leaf[g * 16], 1, __ATOMIC_RELEASE, AGENT);
    }
    if (blockIdx.x == 0) {
        if (threadIdx.x < 63) {
            int expct = (threadIdx.x == 62) ? 2 : 4;   // 62*4 + 2 = 250
            while (__hip_atomic_load(&leaf[threadIdx.x * 16],
                                     __ATOMIC_RELAXED, AGENT) < expct * ep)
                __builtin_amdgcn_s_sleep(1);
        }
        __syncthreads();
        if (threadIdx.x == 0)
            __hip_atomic_store(epoch, ep, __ATOMIC_RELAXED, AGENT);
    } else {
        if (threadIdx.x == 0) {
            while (__hip_atomic_load(epoch, __ATOMIC_RELAXED, AGENT) < ep)
                __builtin_amdgcn_s_sleep(1);
        }
    }
    __builtin_amdgcn_fence(__ATOMIC_ACQUIRE, "workgroup");
    __syncthreads();
}

__global__ __launch_bounds__(TPB, 4) void kmain(
    const float* __restrict__ emb_tab,
    const float* __restrict__ w_ih,
    const float* __restrict__ w_hh,
    const float* __restrict__ b_ih,
    const float* __restrict__ b_hh,
    const float* __restrict__ w_out,
    const float* __restrict__ b_out,
    float* __restrict__ hbuf,   // [T+1][BB*H] rotated h buffers
    float* __restrict__ pq,     // [T][8][NBS][4] packed {sum,max,idxbits,0}
    int* __restrict__ leaf,
    int* __restrict__ epoch,
    float* __restrict__ out)
{
    extern __shared__ float smem[];
    float* w_lds  = smem;
    float* s_h    = smem + SH_OFF;
    float* s_part = smem + SP_OFF;
    float* s_e    = smem + SP_OFF;          // alias: phase-B/C e buffer [8][65]
    float* s_rsum = smem + RS_OFF;
    float* s_rval = smem + RV_OFF;
    int*   s_ridx = (int*)(smem + RI_OFF);
    float* s_S    = smem + SS_OFF;
    int*   s_Xn   = (int*)(smem + XN_OFF);
    int*   s_X    = (int*)(smem + X_OFF);

    const int blk = blockIdx.x, tid = threadIdx.x;

    // ---- stage this block's w_out slice into LDS, swizzled, ONCE ----------
    // layout: w_lds[col*512 + (k ^ ((col&7)<<2) ^ (((k>>5)&7)<<2))]
    for (int i = tid; i < CPB * 128; i += TPB) {
        int col = i >> 7;
        int q4  = (i & 127) << 2;
        int vv  = blk * CPB + col;          // always < V (250*64 == 16000)
        float4 w4 = *(const float4*)(w_out + (size_t)vv * H + q4);
        int sw = q4 ^ ((col & 7) << 2) ^ (((q4 >> 5) & 7) << 2);
        *(float4*)(w_lds + col * 512 + sw) = w4;
    }
    if (tid < BB) s_X[tid] = 1;             // SOS
    __syncthreads();

    // ---- phase-B lane mapping: rh=bits0-1, kq=bits2-5 (16 K-chunks of 32)
    // wave: rowhalf=bit0, col-slot cs=bits1-4; per pass p: col = p*8 + cs
    const int lane = tid & 63;
    const int wv   = tid >> 6;              // 0..15
    const int rh   = lane & 3;
    const int kq   = (lane >> 2) & 15;      // K chunk (32 floats)
    const int rowhalf = wv & 1;
    const int cs   = wv >> 1;               // 0..7
    const int r    = rowhalf * 4 + rh;      // 0..7
    const int xw   = (cs ^ (kq & 7)) << 2;  // w swizzle for this (col-slot,kq)
    const int hswz = (kq & 7) << 2;         // h swizzle for this kq

    // b_out is step-invariant: hoist the 8 per-pass values into VGPRs once
    float bo[8];
#pragma unroll
    for (int p = 0; p < 8; p++) bo[p] = b_out[blk * CPB + p * 8 + cs];

    for (int t = 0; t < T; t++) {
        const float* h_cur = hbuf + (size_t)t * BBH;        // rotated
        float*       h_nxt = hbuf + (size_t)(t + 1) * BBH;  // write-once

        // ---------------- phase A: GRU cell (blocks 0..63) ----------------
        if (blk < 64) {                     // stage h_cur into s_h (plain f4)
            int hr = tid >> 7, k4 = (tid & 127) << 2;
            *(float4*)(s_h + hr * HP + k4) =
                *(const float4*)(h_cur + hr * H + k4);
        }
        __syncthreads();
        if (blk < 64 && tid < 512) {
            const int jl = tid >> 6;        // 0..7
            const int ar = (tid >> 3) & 7;  // row
            const int kq8 = tid & 7;        // K split 8
            const int j  = blk * 8 + jl;
            const int pair = jl * 8 + ar;
            float gir = 0.f, giz = 0.f, gin = 0.f, ghr = 0.f, ghz = 0.f, ghn = 0.f;
            {
                const float* erow = emb_tab + (size_t)s_X[ar] * E;
                const float* w0 = w_ih + (size_t)j * E;
                const float* w1 = w0 + (size_t)H * E;
                const float* w2 = w1 + (size_t)H * E;
                const int k0 = kq8 * (E / 8);
                for (int k = 0; k < E / 8; k += 4) {
                    float4 ev = *(const float4*)(erow + k0 + k);
                    gir += dot4(*(const float4*)(w0 + k0 + k), ev);
                    giz += dot4(*(const float4*)(w1 + k0 + k), ev);
                    gin += dot4(*(const float4*)(w2 + k0 + k), ev);
                }
            }
            {
                const float* hrow = s_h + ar * HP;
                const float* w0 = w_hh + (size_t)j * H;
                const float* w1 = w0 + (size_t)H * H;
                const float* w2 = w1 + (size_t)H * H;
                const int k0 = kq8 * (H / 8);
                for (int k = 0; k < H / 8; k += 4) {
                    float4 hv = *(const float4*)(hrow + k0 + k);
                    ghr += dot4(*(const float4*)(w0 + k0 + k), hv);
                    ghz += dot4(*(const float4*)(w1 + k0 + k), hv);
                    ghn += dot4(*(const float4*)(w2 + k0 + k), hv);
                }
            }
            float* sp = s_part + pair * 48;
            sp[0 * 8 + kq8] = gir; sp[1 * 8 + kq8] = giz; sp[2 * 8 + kq8] = gin;
            sp[3 * 8 + kq8] = ghr; sp[4 * 8 + kq8] = ghz; sp[5 * 8 + kq8] = ghn;
        }
        __syncthreads();
        if (blk < 64 && tid < 512 && (tid & 7) == 0) {
            const int pair = (tid >> 6) * 8 + ((tid >> 3) & 7);
            const int jl = pair >> 3, ar = pair & 7;
            const int j  = blk * 8 + jl;
            const float* sp2 = s_part + pair * 48;
            float G[6];
#pragma unroll
            for (int gg = 0; gg < 6; gg++) {
                float s = 0.f;
#pragma unroll
                for (int q = 0; q < 8; q++) s += sp2[gg * 8 + q];
                G[gg] = s;
            }
            float ir  = G[0] + b_ih[j],         hr_ = G[3] + b_hh[j];
            float iz  = G[1] + b_ih[H + j],     hz  = G[4] + b_hh[H + j];
            float inn = G[2] + b_ih[2 * H + j], hn  = G[5] + b_hh[2 * H + j];
            float rg = 1.f / (1.f + __expf(-(ir + hr_)));
            float zg = 1.f / (1.f + __expf(-(iz + hz)));
            float ng = tanhf(inn + rg * hn);
            float ho = s_h[ar * HP + j];
            int xr = s_X[ar];
            bool dn = (xr == 0) || (xr == 2);
            float hv = dn ? ho : ((1.f - zg) * ng + zg * ho);
            h_nxt[ar * H + j] = hv;         // plain store; flushed by release
        }
        gridbar(leaf, epoch, 2 * t + 1);

        // -------- phase B: logits from LDS-resident w ----------------------
        {   // stage h_nxt, kq-swizzled, plain float4 (first-touch clean)
            int hr = tid >> 7, k4 = (tid & 127) << 2;
            float4 hv4 = *(const float4*)(h_nxt + hr * H + k4);
            int sw = k4 ^ (((k4 >> 5) & 7) << 2);
            *(float4*)(s_h + hr * HP + sw) = hv4;
        }
        __syncthreads();
        {
            // h chunk -> 32 VGPRs, read ONCE per step
            float4 hreg[8];
            const float* hb = s_h + r * HP + kq * 32;
#pragma unroll
            for (int i = 0; i < 8; i++)
                hreg[i] = *(const float4*)(hb + ((4 * i) ^ hswz));

            float s_acc = 0.f, bv = -1.f; int bi = 0x7fffffff;
#pragma unroll
            for (int p = 0; p < 8; p++) {
                const int col = p * 8 + cs;
                const int vv  = blk * CPB + col;
                const float* wb = w_lds + col * 512 + kq * 32;
                float acc = 0.f;
#pragma unroll
                for (int i = 0; i < 8; i++) {
                    float4 w4 = *(const float4*)(wb + ((4 * i) ^ xw));
                    acc += dot4(w4, hreg[i]);
                }
                // full-K sum across the 16 kq lanes (bits 2-5); butterfly is
                // commutative-add -> bitwise identical on every lane
                acc += __shfl_xor(acc, 4, 64);
                acc += __shfl_xor(acc, 8, 64);
                acc += __shfl_xor(acc, 16, 64);
                acc += __shfl_xor(acc, 32, 64);
                float ee = __expf(acc + bo[p]);
                if (kq == 0) s_e[r * 65 + col] = ee;  // stash for phase-C write
                s_acc += ee;
                if (ee > bv) { bv = ee; bi = vv; }  // earlier pass = smaller v
            }
            if (kq == 0) {                  // designated: real per-r results
                s_rsum[wv * 8 + r] = s_acc;
                s_rval[wv * 8 + r] = bv;
                s_ridx[wv * 8 + r] = bi;
            } else if (kq == 1) {           // neutral fill for other row-half
                int ro = (1 - rowhalf) * 4 + rh;
                s_rsum[wv * 8 + ro] = 0.f;
                s_rval[wv * 8 + ro] = -1.f;
                s_ridx[wv * 8 + ro] = 0x7fffffff;
            }
        }
        __syncthreads();
        if (tid < 64) {                     // reduce 16 waves -> per-row, store
            float s  = s_rsum[tid] + s_rsum[tid + 64];
            float av = s_rval[tid], bv2 = s_rval[tid + 64];
            int   ai = s_ridx[tid], bi2 = s_ridx[tid + 64];
            float bv = av; int bi = ai;
            if (bv2 > bv || (bv2 == bv && bi2 < bi)) { bv = bv2; bi = bi2; }
#pragma unroll
            for (int m = 8; m <= 32; m <<= 1) {
                s += __shfl_xor(s, m, 64);
                float ov = __shfl_xor(bv, m, 64);
                int   oi = __shfl_xor(bi, m, 64);
                if (ov > bv || (ov == bv && oi < bi)) { bv = ov; bi = oi; }
            }
            if (tid < 8) {                  // packed triplet, plain store,
                vfloat4 q;                  // rotated buffer (write-once)
                q.x = s; q.y = bv; q.z = __int_as_float(bi); q.w = 0.f;
                *(vfloat4*)(pq + ((size_t)(t * 8 + tid) * NBS + blk) * 4) = q;
            }
        }
        gridbar(leaf, epoch, 2 * t + 2);

        // ------- phase C: parallel reduce (plain coalesced loads) ----------
        if (wv < 8) {
            const float* pqt = pq + (size_t)(t * 8 + wv) * NBS * 4;
            float s = 0.f, bv = -1.f; int bi = 0x7fffffff;
#pragma unroll
            for (int c = 0; c < 4; c++) {
                int idx = lane + 64 * c;
                if (idx < NB) {
                    vfloat4 q = *(const vfloat4*)(pqt + (size_t)idx * 4);
                    s += q.x;
                    float ov = q.y;
                    int   oi = __float_as_int(q.z);
                    if (ov > bv || (ov == bv && oi < bi)) { bv = ov; bi = oi; }
                }
            }
            for (int m = 1; m < 64; m <<= 1) {
                s += __shfl_xor(s, m, 64);
                float ov = __shfl_xor(bv, m, 64);
                int   oi = __shfl_xor(bi, m, 64);
                if (ov > bv || (ov == bv && oi < bi)) { bv = ov; bi = oi; }
            }
            if (lane == 0) { s_S[wv] = s; s_Xn[wv] = bi; }
        }
        __syncthreads();
        {   // out write: FULL-LINE NT vfloat4 stores. Row slice = 256B aligned.
            float* out_t = out + (size_t)t * BB * V;
            if (tid < 128) {
                int row = tid >> 4;         // 0..7
                int c4  = (tid & 15) << 2;  // 0,4,...,60
                int xr = s_X[row];
                bool dn = (xr == 0) || (xr == 2);
                float inv = 1.f / s_S[row];
                int vbase = blk * CPB + c4;
                vfloat4 o4;
                o4.x = dn ? ((vbase + 0 == 0) ? 1.f : 0.f) : s_e[row * 65 + c4 + 0] * inv;
                o4.y = dn ? ((vbase + 1 == 0) ? 1.f : 0.f) : s_e[row * 65 + c4 + 1] * inv;
                o4.z = dn ? ((vbase + 2 == 0) ? 1.f : 0.f) : s_e[row * 65 + c4 + 2] * inv;
                o4.w = dn ? ((vbase + 3 == 0) ? 1.f : 0.f) : s_e[row * 65 + c4 + 3] * inv;
                __builtin_nontemporal_store(o4,
                    (vfloat4*)(out_t + (size_t)row * V + vbase));
            }
        }
        __syncthreads();
        if (tid < 8) {
            int xo = s_X[tid];
            s_X[tid] = ((xo == 0) || (xo == 2)) ? 0 : s_Xn[tid];
        }
        __syncthreads();
    }
}

extern "C" void kernel_launch(void* const* d_in, const int* in_sizes, int n_in,
                              void* d_out, int out_size, void* d_ws, size_t ws_size,
                              hipStream_t stream) {
    (void)in_sizes; (void)n_in; (void)out_size; (void)ws_size;
    const float* hidden    = (const float*)d_in[0];
    const float* embedding = (const float*)d_in[1];
    const float* w_ih      = (const float*)d_in[2];
    const float* w_hh      = (const float*)d_in[3];
    const float* b_ih      = (const float*)d_in[4];
    const float* b_hh      = (const float*)d_in[5];
    const float* w_out     = (const float*)d_in[6];
    const float* b_out     = (const float*)d_in[7];
    float* out = (float*)d_out;

    float* ws    = (float*)d_ws;
    float* hbuf  = ws;                          // (T+1)*BBH = 13*4096 floats
    float* pq    = hbuf + (size_t)(T + 1) * BBH;// T*8*NBS*4 floats (393KB)
    int*   leaf  = (int*)(pq + (size_t)T * 8 * NBS * 4);  // 64*16 counters
    int*   epoch = leaf + 64 * 16;              // 1

    hipFuncSetAttribute((const void*)kmain,
        hipFuncAttributeMaxDynamicSharedMemorySize,
        (int)SMEM_BYTES);

    kinit<<<16, 256, 0, stream>>>(hidden, hbuf, leaf, epoch);
    kmain<<<NB, TPB, SMEM_BYTES, stream>>>(embedding, w_ih, w_hh, b_ih, b_hh,
                                           w_out, b_out, hbuf, pq,
                                           leaf, epoch, out);
}

// Round 9
// 558.591 us; speedup vs baseline: 2.2200x; 1.0959x over previous
//
#include <hip/hip_runtime.h>

#define V 16000
#define E 256
#define H 512
#define HP 516     // padded LDS h row stride (4-float pad: bank groups 4r)
#define BB 8       // batch rows
#define T 12       // lenseq
#define NB 250     // persistent blocks: 250*64 == 16000 exactly (1 block/CU)
#define NBS 256    // pq stride (padded)
#define TPB 1024   // 16 waves/block
#define CPB 64     // vocab cols per block: 64*4B = 256B row slice, LINE-ALIGNED
#define BBH (BB * H)
#define AGENT __HIP_MEMORY_SCOPE_AGENT

typedef float vfloat4 __attribute__((ext_vector_type(4)));
typedef unsigned long long u64;

// Greedy degeneracy verified (R3). Persistent kernel since R4. w_out in LDS
// since R9. Established mechanisms: (i) WRITE_SIZE amplification is invariant
// to store pattern/NT and uncorrelated with dur -> red herring, writer frozen
// (NT full-line). (ii) R15-R17: cross-block data MUST be cache-bypassing
// relaxed atomics; plain stores dirty L2 and the barrier release-add then
// pays writeback (R17 +30us); acquire-spin pays invalidate storms (R16
// +690us); flat barriers pay poll contention (R15 +65us). R14 tree barrier +
// bypass-atomic data path is the proven structure. R18 (this round): shape
// the atomic ops, keep the structure. (1) phase-A h stores: 64 scattered 4B
// agent stores -> LDS gather + 32 coalesced 8B atomic stores; (2) pq packed
// {sum,max} 8B + idx 4B: phase-C 12 -> 8 loads/lane; (3) bar1 producer-only
// arrival on separate leaf lines (rotation makes consumer arrival redundant;
// bar2 stays full-grid so no lapping).

// LDS layout (floats)
constexpr int W_FL   = CPB * 512;            // 32768  swizzled w slice (128KB)
constexpr int SH_OFF = W_FL;                 // s_h   [8][516]
constexpr int SP_OFF = SH_OFF + BB * HP;     // s_part 64*48 (A) / s_e [8][65] (B/C)
constexpr int RS_OFF = SP_OFF + 64 * 48;     // s_rsum [16][8] (+ phase-A h gather)
constexpr int RV_OFF = RS_OFF + 128;         // s_rval
constexpr int RI_OFF = RV_OFF + 128;         // s_ridx (int)
constexpr int SS_OFF = RI_OFF + 128;         // s_S   [8]
constexpr int XN_OFF = SS_OFF + 8;           // s_Xn  [8] (int)
constexpr int X_OFF  = XN_OFF + 8;           // s_X   [8] (int)
constexpr int SMEM_FL = X_OFF + 8;
constexpr size_t SMEM_BYTES = (size_t)SMEM_FL * 4;   // 161,504 B < 160 KiB

// cnt line map (16 ints per line):
//   lines 0..62 : bar2 leaf counters (62x4 + 2 = 250 arrivals)
//   line  63    : epochA word (h-ready publish)
//   lines 64..79: bar1 leaf counters (16 x 4 = 64 producer arrivals)
//   line  80    : epochB word (logits-ready publish)
constexpr int CNT_LINES = 84;

__device__ __forceinline__ float dot4(float4 a, float4 b) {
    return a.x * b.x + a.y * b.y + a.z * b.z + a.w * b.w;
}

__global__ __launch_bounds__(256) void kinit(const float* __restrict__ hidden,
                                             float* __restrict__ hbuf,
                                             int* __restrict__ cnt) {
    int idx = blockIdx.x * 256 + threadIdx.x;
    if (idx < BBH) hbuf[idx] = hidden[idx];
    if (idx < CNT_LINES * 16) cnt[idx] = 0;
}

// bar1: producer-only arrivals (blocks 0..63 on 16 leaf lines) -> block0
// publishes epochA -> everyone polls ONE read-only word RELAXED. (R14
// semantics: RELEASE add, RELAXED polls, workgroup acquire fence.)
__device__ __forceinline__ void barA(int* __restrict__ cnt, int ep) {
    __syncthreads();
    if (blockIdx.x < 64 && threadIdx.x == 0)
        __hip_atomic_fetch_add(&cnt[(64 + (blockIdx.x >> 2)) * 16], 1,
                               __ATOMIC_RELEASE, AGENT);
    if (blockIdx.x == 0) {
        if (threadIdx.x < 16) {
            while (__hip_atomic_load(&cnt[(64 + threadIdx.x) * 16],
                                     __ATOMIC_RELAXED, AGENT) < 4 * ep)
                __builtin_amdgcn_s_sleep(1);
        }
        __syncthreads();
        if (threadIdx.x == 0)
            __hip_atomic_store(&cnt[63 * 16], ep, __ATOMIC_RELAXED, AGENT);
    } else {
        if (threadIdx.x == 0) {
            while (__hip_atomic_load(&cnt[63 * 16], __ATOMIC_RELAXED, AGENT) < ep)
                __builtin_amdgcn_s_sleep(1);
        }
    }
    __builtin_amdgcn_fence(__ATOMIC_ACQUIRE, "workgroup");
    __syncthreads();
}

// bar2: full-grid, R14 tree VERBATIM (63 leaves; leaf 62 has 2 blocks).
__device__ __forceinline__ void barB(int* __restrict__ cnt, int ep) {
    __syncthreads();
    if (threadIdx.x == 0) {
        int g = blockIdx.x >> 2;
        __hip_atomic_fetch_add(&cnt[g * 16], 1, __ATOMIC_RELEASE, AGENT);
    }
    if (blockIdx.x == 0) {
        if (threadIdx.x < 63) {
            int expct = (threadIdx.x == 62) ? 2 : 4;   // 62*4 + 2 = 250
            while (__hip_atomic_load(&cnt[threadIdx.x * 16],
                                     __ATOMIC_RELAXED, AGENT) < expct * ep)
                __builtin_amdgcn_s_sleep(1);
        }
        __syncthreads();
        if (threadIdx.x == 0)
            __hip_atomic_store(&cnt[80 * 16], ep, __ATOMIC_RELAXED, AGENT);
    } else {
        if (threadIdx.x == 0) {
            while (__hip_atomic_load(&cnt[80 * 16], __ATOMIC_RELAXED, AGENT) < ep)
                __builtin_amdgcn_s_sleep(1);
        }
    }
    __builtin_amdgcn_fence(__ATOMIC_ACQUIRE, "workgroup");
    __syncthreads();
}

__global__ __launch_bounds__(TPB, 4) void kmain(
    const float* __restrict__ emb_tab,
    const float* __restrict__ w_ih,
    const float* __restrict__ w_hh,
    const float* __restrict__ b_ih,
    const float* __restrict__ b_hh,
    const float* __restrict__ w_out,
    const float* __restrict__ b_out,
    float* __restrict__ hbuf,   // [T+1][BB*H] rotated h buffers
    u64* __restrict__ pqm,      // [T][8][NBS] packed {sum,max}
    int* __restrict__ pqi,      // [T][8][NBS] argmax idx
    int* __restrict__ cnt,
    float* __restrict__ out)
{
    extern __shared__ float smem[];
    float* w_lds  = smem;
    float* s_h    = smem + SH_OFF;
    float* s_part = smem + SP_OFF;
    float* s_e    = smem + SP_OFF;          // alias: phase-B/C e buffer [8][65]
    float* s_rsum = smem + RS_OFF;
    float* s_rval = smem + RV_OFF;
    int*   s_ridx = (int*)(smem + RI_OFF);
    float* s_S    = smem + SS_OFF;
    int*   s_Xn   = (int*)(smem + XN_OFF);
    int*   s_X    = (int*)(smem + X_OFF);

    const int blk = blockIdx.x, tid = threadIdx.x;

    // ---- stage this block's w_out slice into LDS, swizzled, ONCE ----------
    // layout: w_lds[col*512 + (k ^ ((col&7)<<2) ^ (((k>>5)&7)<<2))]
    for (int i = tid; i < CPB * 128; i += TPB) {
        int col = i >> 7;
        int q4  = (i & 127) << 2;
        int vv  = blk * CPB + col;          // always < V (250*64 == 16000)
        float4 w4 = *(const float4*)(w_out + (size_t)vv * H + q4);
        int sw = q4 ^ ((col & 7) << 2) ^ (((q4 >> 5) & 7) << 2);
        *(float4*)(w_lds + col * 512 + sw) = w4;
    }
    if (tid < BB) s_X[tid] = 1;             // SOS
    __syncthreads();

    // ---- phase-B lane mapping: rh=bits0-1, kq=bits2-5 (16 K-chunks of 32)
    // wave: rowhalf=bit0, col-slot cs=bits1-4; per pass p: col = p*8 + cs
    const int lane = tid & 63;
    const int wv   = tid >> 6;              // 0..15
    const int rh   = lane & 3;
    const int kq   = (lane >> 2) & 15;      // K chunk (32 floats)
    const int rowhalf = wv & 1;
    const int cs   = wv >> 1;               // 0..7
    const int r    = rowhalf * 4 + rh;      // 0..7
    const int xw   = (cs ^ (kq & 7)) << 2;  // w swizzle for this (col-slot,kq)
    const int hswz = (kq & 7) << 2;         // h swizzle for this kq

    // b_out is step-invariant: hoist the 8 per-pass values into VGPRs once
    float bo[8];
#pragma unroll
    for (int p = 0; p < 8; p++) bo[p] = b_out[blk * CPB + p * 8 + cs];

    for (int t = 0; t < T; t++) {
        const float* h_cur = hbuf + (size_t)t * BBH;        // rotated
        float*       h_nxt = hbuf + (size_t)(t + 1) * BBH;  // write-once

        // ---------------- phase A: GRU cell (blocks 0..63) ----------------
        if (blk < 64) {                     // stage h_cur (8B atomic loads)
            int hr = tid >> 7, k4 = (tid & 127) << 2;
            const u64* p = (const u64*)(h_cur + hr * H + k4);
            union { u64 u; float f[2]; } c0, c1;
            c0.u = __hip_atomic_load(p,     __ATOMIC_RELAXED, AGENT);
            c1.u = __hip_atomic_load(p + 1, __ATOMIC_RELAXED, AGENT);
            *(float4*)(s_h + hr * HP + k4) =
                make_float4(c0.f[0], c0.f[1], c1.f[0], c1.f[1]);
        }
        __syncthreads();
        if (blk < 64 && tid < 512) {
            const int jl = tid >> 6;        // 0..7
            const int ar = (tid >> 3) & 7;  // row
            const int kq8 = tid & 7;        // K split 8
            const int j  = blk * 8 + jl;
            const int pair = jl * 8 + ar;
            float gir = 0.f, giz = 0.f, gin = 0.f, ghr = 0.f, ghz = 0.f, ghn = 0.f;
            {
                const float* erow = emb_tab + (size_t)s_X[ar] * E;
                const float* w0 = w_ih + (size_t)j * E;
                const float* w1 = w0 + (size_t)H * E;
                const float* w2 = w1 + (size_t)H * E;
                const int k0 = kq8 * (E / 8);
                for (int k = 0; k < E / 8; k += 4) {
                    float4 ev = *(const float4*)(erow + k0 + k);
                    gir += dot4(*(const float4*)(w0 + k0 + k), ev);
                    giz += dot4(*(const float4*)(w1 + k0 + k), ev);
                    gin += dot4(*(const float4*)(w2 + k0 + k), ev);
                }
            }
            {
                const float* hrow = s_h + ar * HP;
                const float* w0 = w_hh + (size_t)j * H;
                const float* w1 = w0 + (size_t)H * H;
                const float* w2 = w1 + (size_t)H * H;
                const int k0 = kq8 * (H / 8);
                for (int k = 0; k < H / 8; k += 4) {
                    float4 hv = *(const float4*)(hrow + k0 + k);
                    ghr += dot4(*(const float4*)(w0 + k0 + k), hv);
                    ghz += dot4(*(const float4*)(w1 + k0 + k), hv);
                    ghn += dot4(*(const float4*)(w2 + k0 + k), hv);
                }
            }
            float* sp = s_part + pair * 48;
            sp[0 * 8 + kq8] = gir; sp[1 * 8 + kq8] = giz; sp[2 * 8 + kq8] = gin;
            sp[3 * 8 + kq8] = ghr; sp[4 * 8 + kq8] = ghz; sp[5 * 8 + kq8] = ghn;
        }
        __syncthreads();
        if (blk < 64 && tid < 512 && (tid & 7) == 0) {
            const int pair = (tid >> 6) * 8 + ((tid >> 3) & 7);
            const int jl = pair >> 3, ar = pair & 7;
            const int j  = blk * 8 + jl;
            const float* sp2 = s_part + pair * 48;
            float G[6];
#pragma unroll
            for (int gg = 0; gg < 6; gg++) {
                float s = 0.f;
#pragma unroll
                for (int q = 0; q < 8; q++) s += sp2[gg * 8 + q];
                G[gg] = s;
            }
            float ir  = G[0] + b_ih[j],         hr_ = G[3] + b_hh[j];
            float iz  = G[1] + b_ih[H + j],     hz  = G[4] + b_hh[H + j];
            float inn = G[2] + b_ih[2 * H + j], hn  = G[5] + b_hh[2 * H + j];
            float rg = 1.f / (1.f + __expf(-(ir + hr_)));
            float zg = 1.f / (1.f + __expf(-(iz + hz)));
            float ng = tanhf(inn + rg * hn);
            float ho = s_h[ar * HP + j];
            int xr = s_X[ar];
            bool dn = (xr == 0) || (xr == 2);
            float hv = dn ? ho : ((1.f - zg) * ng + zg * ho);
            s_rsum[ar * 8 + jl] = hv;       // gather for packed store
        }
        __syncthreads();
        if (blk < 64 && tid < 32) {         // 32 coalesced 8B bypass stores
            int ar = tid >> 2, q2 = (tid & 3) << 1;
            union { float f[2]; u64 u; } pk;
            pk.f[0] = s_rsum[ar * 8 + q2];
            pk.f[1] = s_rsum[ar * 8 + q2 + 1];
            __hip_atomic_store((u64*)(h_nxt + (size_t)ar * H + blk * 8 + q2),
                               pk.u, __ATOMIC_RELAXED, AGENT);
        }
        barA(cnt, t + 1);

        // -------- phase B: logits from LDS-resident w ----------------------
        {   // stage h_nxt, kq-swizzled (8B atomic loads)
            int hr = tid >> 7, k4 = (tid & 127) << 2;
            const u64* p = (const u64*)(h_nxt + hr * H + k4);
            union { u64 u; float f[2]; } c0, c1;
            c0.u = __hip_atomic_load(p,     __ATOMIC_RELAXED, AGENT);
            c1.u = __hip_atomic_load(p + 1, __ATOMIC_RELAXED, AGENT);
            int sw = k4 ^ (((k4 >> 5) & 7) << 2);
            *(float4*)(s_h + hr * HP + sw) =
                make_float4(c0.f[0], c0.f[1], c1.f[0], c1.f[1]);
        }
        __syncthreads();
        {
            // h chunk -> 32 VGPRs, read ONCE per step
            float4 hreg[8];
            const float* hb = s_h + r * HP + kq * 32;
#pragma unroll
            for (int i = 0; i < 8; i++)
                hreg[i] = *(const float4*)(hb + ((4 * i) ^ hswz));

            float s_acc = 0.f, bv = -1.f; int bi = 0x7fffffff;
#pragma unroll
            for (int p = 0; p < 8; p++) {
                const int col = p * 8 + cs;
                const int vv  = blk * CPB + col;
                const float* wb = w_lds + col * 512 + kq * 32;
                float acc = 0.f;
#pragma unroll
                for (int i = 0; i < 8; i++) {
                    float4 w4 = *(const float4*)(wb + ((4 * i) ^ xw));
                    acc += dot4(w4, hreg[i]);
                }
                // full-K sum across the 16 kq lanes (bits 2-5); butterfly is
                // commutative-add -> bitwise identical on every lane
                acc += __shfl_xor(acc, 4, 64);
                acc += __shfl_xor(acc, 8, 64);
                acc += __shfl_xor(acc, 16, 64);
                acc += __shfl_xor(acc, 32, 64);
                float ee = __expf(acc + bo[p]);
                if (kq == 0) s_e[r * 65 + col] = ee;  // stash for phase-C write
                s_acc += ee;
                if (ee > bv) { bv = ee; bi = vv; }  // earlier pass = smaller v
            }
            if (kq == 0) {                  // designated: real per-r results
                s_rsum[wv * 8 + r] = s_acc;
                s_rval[wv * 8 + r] = bv;
                s_ridx[wv * 8 + r] = bi;
            } else if (kq == 1) {           // neutral fill for other row-half
                int ro = (1 - rowhalf) * 4 + rh;
                s_rsum[wv * 8 + ro] = 0.f;
                s_rval[wv * 8 + ro] = -1.f;
                s_ridx[wv * 8 + ro] = 0x7fffffff;
            }
        }
        __syncthreads();
        if (tid < 64) {                     // reduce 16 waves -> per-row, store
            float s  = s_rsum[tid] + s_rsum[tid + 64];
            float av = s_rval[tid], bv2 = s_rval[tid + 64];
            int   ai = s_ridx[tid], bi2 = s_ridx[tid + 64];
            float bv = av; int bi = ai;
            if (bv2 > bv || (bv2 == bv && bi2 < bi)) { bv = bv2; bi = bi2; }
#pragma unroll
            for (int m = 8; m <= 32; m <<= 1) {
                s += __shfl_xor(s, m, 64);
                float ov = __shfl_xor(bv, m, 64);
                int   oi = __shfl_xor(bi, m, 64);
                if (ov > bv || (ov == bv && oi < bi)) { bv = ov; bi = oi; }
            }
            if (tid < 8) {                  // packed {sum,max} 8B + idx 4B
                union { float f[2]; u64 u; } pk;
                pk.f[0] = s; pk.f[1] = bv;
                size_t o = (size_t)(t * 8 + tid) * NBS + blk;
                __hip_atomic_store(&pqm[o], pk.u, __ATOMIC_RELAXED, AGENT);
                __hip_atomic_store(&pqi[o], bi,   __ATOMIC_RELAXED, AGENT);
            }
        }
        barB(cnt, t + 1);

        // ------- phase C: redundant reduce (packed bypass loads) -----------
        if (wv < 8) {
            const size_t base = (size_t)(t * 8 + wv) * NBS;
            float s = 0.f, bv = -1.f; int bi = 0x7fffffff;
#pragma unroll
            for (int c = 0; c < 4; c++) {
                int idx = lane + 64 * c;
                if (idx < NB) {
                    union { float f[2]; u64 u; } pk;
                    pk.u = __hip_atomic_load(&pqm[base + idx],
                                             __ATOMIC_RELAXED, AGENT);
                    s += pk.f[0];
                    float ov = pk.f[1];
                    int   oi = __hip_atomic_load(&pqi[base + idx],
                                                 __ATOMIC_RELAXED, AGENT);
                    if (ov > bv || (ov == bv && oi < bi)) { bv = ov; bi = oi; }
                }
            }
            for (int m = 1; m < 64; m <<= 1) {
                s += __shfl_xor(s, m, 64);
                float ov = __shfl_xor(bv, m, 64);
                int   oi = __shfl_xor(bi, m, 64);
                if (ov > bv || (ov == bv && oi < bi)) { bv = ov; bi = oi; }
            }
            if (lane == 0) { s_S[wv] = s; s_Xn[wv] = bi; }
        }
        __syncthreads();
        {   // out write: FULL-LINE NT vfloat4 stores. Row slice = 256B aligned.
            float* out_t = out + (size_t)t * BB * V;
            if (tid < 128) {
                int row = tid >> 4;         // 0..7
                int c4  = (tid & 15) << 2;  // 0,4,...,60
                int xr = s_X[row];
                bool dn = (xr == 0) || (xr == 2);
                float inv = 1.f / s_S[row];
                int vbase = blk * CPB + c4;
                vfloat4 o4;
                o4.x = dn ? ((vbase + 0 == 0) ? 1.f : 0.f) : s_e[row * 65 + c4 + 0] * inv;
                o4.y = dn ? ((vbase + 1 == 0) ? 1.f : 0.f) : s_e[row * 65 + c4 + 1] * inv;
                o4.z = dn ? ((vbase + 2 == 0) ? 1.f : 0.f) : s_e[row * 65 + c4 + 2] * inv;
                o4.w = dn ? ((vbase + 3 == 0) ? 1.f : 0.f) : s_e[row * 65 + c4 + 3] * inv;
                __builtin_nontemporal_store(o4,
                    (vfloat4*)(out_t + (size_t)row * V + vbase));
            }
        }
        __syncthreads();
        if (tid < 8) {
            int xo = s_X[tid];
            s_X[tid] = ((xo == 0) || (xo == 2)) ? 0 : s_Xn[tid];
        }
        __syncthreads();
    }
}

extern "C" void kernel_launch(void* const* d_in, const int* in_sizes, int n_in,
                              void* d_out, int out_size, void* d_ws, size_t ws_size,
                              hipStream_t stream) {
    (void)in_sizes; (void)n_in; (void)out_size; (void)ws_size;
    const float* hidden    = (const float*)d_in[0];
    const float* embedding = (const float*)d_in[1];
    const float* w_ih      = (const float*)d_in[2];
    const float* w_hh      = (const float*)d_in[3];
    const float* b_ih      = (const float*)d_in[4];
    const float* b_hh      = (const float*)d_in[5];
    const float* w_out     = (const float*)d_in[6];
    const float* b_out     = (const float*)d_in[7];
    float* out = (float*)d_out;

    float* ws    = (float*)d_ws;
    float* hbuf  = ws;                            // (T+1)*BBH floats
    u64*   pqm   = (u64*)(hbuf + (size_t)(T + 1) * BBH);   // T*8*NBS u64
    int*   pqi   = (int*)(pqm + (size_t)T * 8 * NBS);      // T*8*NBS int
    int*   cnt   = pqi + (size_t)T * 8 * NBS;              // CNT_LINES*16

    hipFuncSetAttribute((const void*)kmain,
        hipFuncAttributeMaxDynamicSharedMemorySize,
        (int)SMEM_BYTES);

    kinit<<<16, 256, 0, stream>>>(hidden, hbuf, cnt);
    kmain<<<NB, TPB, SMEM_BYTES, stream>>>(embedding, w_ih, w_hh, b_ih, b_hh,
                                           w_out, b_out, hbuf, pqm, pqi,
                                           cnt, out);
}